// Round 1
// baseline (5838.359 us; speedup 1.0000x reference)
//
#include <hip/hip_runtime.h>

#define BB 4
#define LL 512
#define DD 768
#define NLAYER 12
#define DI 1536
#define NS 16
#define KC 4
#define RR 48
#define MROWS (BB*LL)   // 2048
#define E2 (2*DI)       // 3072
#define EPSV 1e-5f

typedef __attribute__((ext_vector_type(8))) short bf16x8;
typedef __attribute__((ext_vector_type(4))) float f32x4;

__device__ inline ushort f2bf(float f) {
  union { float f; unsigned u; } v; v.f = f;
  unsigned u = v.u;
  unsigned r = (u + 0x7fffu + ((u >> 16) & 1u)) >> 16;
  return (ushort)r;
}

// ---------------- embedding: resid = wte[ids] + wpe ----------------
__global__ __launch_bounds__(256) void k_embed(const int* __restrict__ ids,
    const float* __restrict__ wte, const float* __restrict__ wpe,
    float* __restrict__ resid) {
  const int nd4 = DD / 4; // 192
  int i = blockIdx.x * 256 + threadIdx.x;
  if (i >= MROWS * nd4) return;
  int m = i / nd4, d4 = i - m * nd4;
  int l = m & (LL - 1);
  int tok = ids[m];
  float4 a = ((const float4*)wte)[(size_t)tok * nd4 + d4];
  float4 b = ((const float4*)wpe)[(size_t)l * nd4 + d4];
  float4 o; o.x = a.x + b.x; o.y = a.y + b.y; o.z = a.z + b.z; o.w = a.w + b.w;
  ((float4*)resid)[i] = o;
}

// ---------------- block reduction helper (256 threads = 4 waves) ----------------
__device__ inline float block_sum(float v, volatile float* red) {
  #pragma unroll
  for (int o = 32; o > 0; o >>= 1) v += __shfl_down(v, o);
  if ((threadIdx.x & 63) == 0) red[threadIdx.x >> 6] = v;
  __syncthreads();
  float t = red[0] + red[1] + red[2] + red[3];
  __syncthreads();
  return t;
}

// ---------------- fused residual add + layernorm -> bf16 ----------------
__global__ __launch_bounds__(256) void k_ln(const float* __restrict__ hid,
    float* __restrict__ resid, const float* __restrict__ g, const float* __restrict__ b,
    ushort* __restrict__ hbf, int addHidden) {
  __shared__ float red[4];
  int m = blockIdx.x, t = threadIdx.x;
  size_t base = (size_t)m * DD;
  float x0 = resid[base + t], x1 = resid[base + t + 256], x2 = resid[base + t + 512];
  if (addHidden) {
    x0 += hid[base + t]; x1 += hid[base + t + 256]; x2 += hid[base + t + 512];
    resid[base + t] = x0; resid[base + t + 256] = x1; resid[base + t + 512] = x2;
  }
  float S  = block_sum(x0 + x1 + x2, red);
  float S2 = block_sum(x0*x0 + x1*x1 + x2*x2, red);
  float mu = S * (1.f / DD);
  float var = S2 * (1.f / DD) - mu * mu;
  float rs = rsqrtf(var + EPSV);
  hbf[base + t]       = f2bf((x0 - mu) * rs * g[t]       + b[t]);
  hbf[base + t + 256] = f2bf((x1 - mu) * rs * g[t + 256] + b[t + 256]);
  hbf[base + t + 512] = f2bf((x2 - mu) * rs * g[t + 512] + b[t + 512]);
}

// ---------------- generic NT bf16 MFMA GEMM: C[m,n] = sum_k A[m,k]*B[n,k] ----------------
// A: M x K bf16 row-major, Bw: N x K bf16 row-major, C: M x N f32.
// Requires M % 64 == 0, K % 32 == 0. N arbitrary (bounds-checked).
__global__ __launch_bounds__(256) void k_gemm(const ushort* __restrict__ A,
    const ushort* __restrict__ Bw, float* __restrict__ C, int M, int N, int K) {
  __shared__ short lA[64][40];
  __shared__ short lB[64][40];
  int tid = threadIdx.x;
  int tm = blockIdx.y * 64, tn = blockIdx.x * 64;
  int wid = tid >> 6, lane = tid & 63;
  int wr = (wid >> 1) * 32, wc = (wid & 1) * 32;
  int fr = lane & 15, kg = lane >> 4;
  int ldr = tid >> 2, ldc = (tid & 3) * 8;
  f32x4 acc[2][2];
  #pragma unroll
  for (int mi = 0; mi < 2; ++mi)
    #pragma unroll
    for (int ni = 0; ni < 2; ++ni)
      acc[mi][ni] = {0.f, 0.f, 0.f, 0.f};

  for (int k0 = 0; k0 < K; k0 += 32) {
    __syncthreads();
    bf16x8 va = *(const bf16x8*)(A + (size_t)(tm + ldr) * K + k0 + ldc);
    short z = 0;
    bf16x8 vb = {z, z, z, z, z, z, z, z};
    int brow = tn + ldr;
    if (brow < N) vb = *(const bf16x8*)(Bw + (size_t)brow * K + k0 + ldc);
    *(bf16x8*)&lA[ldr][ldc] = va;
    *(bf16x8*)&lB[ldr][ldc] = vb;
    __syncthreads();
    bf16x8 a0 = *(const bf16x8*)&lA[wr + fr][kg * 8];
    bf16x8 a1 = *(const bf16x8*)&lA[wr + 16 + fr][kg * 8];
    bf16x8 b0 = *(const bf16x8*)&lB[wc + fr][kg * 8];
    bf16x8 b1 = *(const bf16x8*)&lB[wc + 16 + fr][kg * 8];
    acc[0][0] = __builtin_amdgcn_mfma_f32_16x16x32_bf16(a0, b0, acc[0][0], 0, 0, 0);
    acc[0][1] = __builtin_amdgcn_mfma_f32_16x16x32_bf16(a0, b1, acc[0][1], 0, 0, 0);
    acc[1][0] = __builtin_amdgcn_mfma_f32_16x16x32_bf16(a1, b0, acc[1][0], 0, 0, 0);
    acc[1][1] = __builtin_amdgcn_mfma_f32_16x16x32_bf16(a1, b1, acc[1][1], 0, 0, 0);
  }
  int crow0 = tm + wr + (lane >> 4) * 4;
  int ccol0 = tn + wc + fr;
  #pragma unroll
  for (int mi = 0; mi < 2; ++mi)
    #pragma unroll
    for (int ni = 0; ni < 2; ++ni) {
      int cc = ccol0 + ni * 16;
      if (cc < N) {
        #pragma unroll
        for (int j = 0; j < 4; ++j)
          C[(size_t)(crow0 + mi * 16 + j) * N + cc] = acc[mi][ni][j];
      }
    }
}

// ---------------- causal depthwise conv (K=4) + silu, writes f32 + bf16 ----------------
__global__ __launch_bounds__(256) void k_conv(const float* __restrict__ xz,
    const float* __restrict__ cW, const float* __restrict__ cb,
    float* __restrict__ xif, ushort* __restrict__ xibf, int layer) {
  int i = blockIdx.x * 256 + threadIdx.x;
  if (i >= MROWS * DI) return;
  int c = i % DI;
  int m = i / DI;
  int l = m & (LL - 1);
  const float* w = cW + ((size_t)layer * DI + c) * KC;
  float acc = cb[(size_t)layer * DI + c];
  #pragma unroll
  for (int k = 0; k < KC; ++k) {
    int ll = l - (KC - 1) + k;
    if (ll >= 0) acc += xz[(size_t)(m - (KC - 1) + k) * E2 + c] * w[k];
  }
  float sg = 1.f / (1.f + __expf(-acc));
  float v = acc * sg;
  xif[i] = v;
  xibf[i] = f2bf(v);
}

// ---------------- weight f32 -> bf16 (vectorized x4) ----------------
__global__ __launch_bounds__(256) void k_cvt4(const float* __restrict__ s,
    ushort* __restrict__ d, int n4) {
  int i = blockIdx.x * 256 + threadIdx.x;
  if (i >= n4) return;
  float4 v = ((const float4*)s)[i];
  ushort4 o = { f2bf(v.x), f2bf(v.y), f2bf(v.z), f2bf(v.w) };
  ((ushort4*)d)[i] = o;
}

// dt_W (DI x 48) -> bf16 (DI x 64), zero-padded K
__global__ __launch_bounds__(256) void k_cvt_dtw(const float* __restrict__ s,
    ushort* __restrict__ d) {
  int i = blockIdx.x * 256 + threadIdx.x;
  if (i >= DI * 64) return;
  int r = i >> 6, c = i & 63;
  d[i] = (c < RR) ? f2bf(s[r * RR + c]) : (ushort)0;
}

// dbl (MROWS x 80) first 48 cols -> dt_bf (MROWS x 64), zero-padded K
__global__ __launch_bounds__(256) void k_cvt_dta(const float* __restrict__ dblb,
    ushort* __restrict__ dtbf) {
  int i = blockIdx.x * 256 + threadIdx.x;
  if (i >= MROWS * 64) return;
  int r = i >> 6, c = i & 63;
  dtbf[i] = (c < RR) ? f2bf(dblb[r * 80 + c]) : (ushort)0;
}

// ---------------- selective scan: thread per (b,d,n); xor-reduce over n ----------------
__global__ __launch_bounds__(256) void k_scan(const float* __restrict__ draw,
    const float* __restrict__ uf, const float* __restrict__ dblb,
    const float* __restrict__ xz, const float* __restrict__ A_log,
    const float* __restrict__ dt_b, const float* __restrict__ Dres,
    ushort* __restrict__ ybf, int layer) {
  int tid = threadIdx.x;
  int chan = blockIdx.x * 16 + (tid >> 4);
  int n = tid & 15;
  int b = chan / DI;
  int d = chan - b * DI;
  float an = -__expf(A_log[((size_t)layer * DI + d) * NS + n]);
  float dtbv = dt_b[(size_t)layer * DI + d];
  float dresv = Dres[(size_t)layer * DI + d];
  float h = 0.f;
  size_t rD = (size_t)b * LL * DI + d;
  size_t rBC = (size_t)b * LL * 80;
  size_t rZ = (size_t)b * LL * E2 + DI + d;
  size_t rY = rD;
  float nd = draw[rD], nu = uf[rD];
  float nb = dblb[rBC + RR + n], nc = dblb[rBC + RR + NS + n];
  float nz = xz[rZ];
  for (int l = 0; l < LL; ++l) {
    float dv = nd, uv = nu, bv = nb, cv = nc, zv = nz;
    if (l + 1 < LL) {
      rD += DI; rBC += 80; rZ += E2;
      nd = draw[rD]; nu = uf[rD];
      nb = dblb[rBC + RR + n]; nc = dblb[rBC + RR + NS + n];
      nz = xz[rZ];
    }
    float xx = dv + dtbv;
    float delta = (xx > 20.f) ? xx : log1pf(__expf(xx));
    float dA = __expf(delta * an);
    h = h * dA + (delta * uv) * bv;
    float y = h * cv;
    y += __shfl_xor(y, 1);
    y += __shfl_xor(y, 2);
    y += __shfl_xor(y, 4);
    y += __shfl_xor(y, 8);
    if (n == 0) {
      float yt = y + uv * dresv;
      float sg = 1.f / (1.f + __expf(-zv));
      ybf[rY] = f2bf(yt * (zv * sg));
    }
    rY += DI;
  }
}

// ---------------- final: resid += hidden; out = LN(LN(resid,nf),fin) ----------------
__global__ __launch_bounds__(256) void k_final(const float* __restrict__ resid,
    const float* __restrict__ hid, const float* __restrict__ nfg,
    const float* __restrict__ nfb, const float* __restrict__ fig,
    const float* __restrict__ fib, float* __restrict__ out) {
  __shared__ float red[4];
  int m = blockIdx.x, t = threadIdx.x;
  size_t base = (size_t)m * DD;
  float x0 = resid[base + t]       + hid[base + t];
  float x1 = resid[base + t + 256] + hid[base + t + 256];
  float x2 = resid[base + t + 512] + hid[base + t + 512];
  float S  = block_sum(x0 + x1 + x2, red);
  float S2 = block_sum(x0*x0 + x1*x1 + x2*x2, red);
  float mu = S * (1.f / DD);
  float var = S2 * (1.f / DD) - mu * mu;
  float rs = rsqrtf(var + EPSV);
  float t0 = (x0 - mu) * rs * nfg[t]       + nfb[t];
  float t1 = (x1 - mu) * rs * nfg[t + 256] + nfb[t + 256];
  float t2 = (x2 - mu) * rs * nfg[t + 512] + nfb[t + 512];
  S  = block_sum(t0 + t1 + t2, red);
  S2 = block_sum(t0*t0 + t1*t1 + t2*t2, red);
  mu = S * (1.f / DD);
  var = S2 * (1.f / DD) - mu * mu;
  rs = rsqrtf(var + EPSV);
  out[base + t]       = (t0 - mu) * rs * fig[t]       + fib[t];
  out[base + t + 256] = (t1 - mu) * rs * fig[t + 256] + fib[t + 256];
  out[base + t + 512] = (t2 - mu) * rs * fig[t + 512] + fib[t + 512];
}

extern "C" void kernel_launch(void* const* d_in, const int* in_sizes, int n_in,
                              void* d_out, int out_size, void* d_ws, size_t ws_size,
                              hipStream_t stream) {
  const int*   ids    = (const int*)  d_in[0];
  const float* wte    = (const float*)d_in[1];
  const float* wpe    = (const float*)d_in[2];
  const float* ln_g   = (const float*)d_in[3];
  const float* ln_b   = (const float*)d_in[4];
  const float* in_W   = (const float*)d_in[5];
  const float* conv_W = (const float*)d_in[6];
  const float* conv_b = (const float*)d_in[7];
  const float* xp_W   = (const float*)d_in[8];
  const float* dt_W   = (const float*)d_in[9];
  const float* dt_b   = (const float*)d_in[10];
  const float* A_log  = (const float*)d_in[11];
  const float* Dres   = (const float*)d_in[12];
  const float* out_W  = (const float*)d_in[13];
  const float* nf_g   = (const float*)d_in[14];
  const float* nf_b   = (const float*)d_in[15];
  const float* fin_g  = (const float*)d_in[16];
  const float* fin_b  = (const float*)d_in[17];

  char* p = (char*)d_ws;
  auto take = [&](size_t bytes) {
    char* r = p; p += (bytes + 255) & ~(size_t)255; return r;
  };
  float*  resid  = (float*) take((size_t)MROWS * DD * 4);
  float*  hidden = (float*) take((size_t)MROWS * DD * 4);
  ushort* h_bf   = (ushort*)take((size_t)MROWS * DD * 2);
  float*  xz     = (float*) take((size_t)MROWS * E2 * 4);
  float*  xif    = (float*) take((size_t)MROWS * DI * 4);
  ushort* xibf   = (ushort*)take((size_t)MROWS * DI * 2);
  float*  dblb   = (float*) take((size_t)MROWS * 80 * 4);
  ushort* dtbf   = (ushort*)take((size_t)MROWS * 64 * 2);
  float*  draw   = (float*) take((size_t)MROWS * DI * 4);
  ushort* ybf    = (ushort*)take((size_t)MROWS * DI * 2);
  ushort* wInBf  = (ushort*)take((size_t)E2 * DD * 2);
  ushort* wXpBf  = (ushort*)take((size_t)80 * DI * 2);
  ushort* wDtBf  = (ushort*)take((size_t)DI * 64 * 2);
  ushort* wOutBf = (ushort*)take((size_t)DD * DI * 2);

  k_embed<<<(MROWS * (DD / 4) + 255) / 256, 256, 0, stream>>>(ids, wte, wpe, resid);

  for (int i = 0; i < NLAYER; ++i) {
    k_cvt4<<<((E2 * DD / 4) + 255) / 256, 256, 0, stream>>>(
        in_W + (size_t)i * E2 * DD, wInBf, E2 * DD / 4);
    k_cvt4<<<((80 * DI / 4) + 255) / 256, 256, 0, stream>>>(
        xp_W + (size_t)i * 80 * DI, wXpBf, 80 * DI / 4);
    k_cvt_dtw<<<((DI * 64) + 255) / 256, 256, 0, stream>>>(
        dt_W + (size_t)i * DI * RR, wDtBf);
    k_cvt4<<<((DD * DI / 4) + 255) / 256, 256, 0, stream>>>(
        out_W + (size_t)i * DD * DI, wOutBf, DD * DI / 4);

    k_ln<<<MROWS, 256, 0, stream>>>(hidden, resid, ln_g + (size_t)i * DD,
                                    ln_b + (size_t)i * DD, h_bf, i > 0 ? 1 : 0);

    { dim3 g((E2 + 63) / 64, MROWS / 64);
      k_gemm<<<g, 256, 0, stream>>>(h_bf, wInBf, xz, MROWS, E2, DD); }

    k_conv<<<((MROWS * DI) + 255) / 256, 256, 0, stream>>>(
        xz, conv_W, conv_b, xif, xibf, i);

    { dim3 g((80 + 63) / 64, MROWS / 64);
      k_gemm<<<g, 256, 0, stream>>>(xibf, wXpBf, dblb, MROWS, 80, DI); }

    k_cvt_dta<<<((MROWS * 64) + 255) / 256, 256, 0, stream>>>(dblb, dtbf);

    { dim3 g((DI + 63) / 64, MROWS / 64);
      k_gemm<<<g, 256, 0, stream>>>(dtbf, wDtBf, draw, MROWS, DI, 64); }

    k_scan<<<BB * DI / 16, 256, 0, stream>>>(draw, xif, dblb, xz, A_log,
                                             dt_b, Dres, ybf, i);

    { dim3 g((DD + 63) / 64, MROWS / 64);
      k_gemm<<<g, 256, 0, stream>>>(ybf, wOutBf, hidden, MROWS, DD, DI); }
  }

  k_final<<<MROWS, 256, 0, stream>>>(resid, hidden, nf_g, nf_b,
                                     fin_g, fin_b, (float*)d_out);
}

// Round 2
// 2142.131 us; speedup vs baseline: 2.7255x; 2.7255x over previous
//
#include <hip/hip_runtime.h>

#define BB 4
#define LL 512
#define DD 768
#define NLAYER 12
#define DI 1536
#define NS 16
#define KC 4
#define RR 48
#define MROWS (BB*LL)   // 2048
#define E2 (2*DI)       // 3072
#define EPSV 1e-5f
#define CHK 32
#define LC (LL/CHK)     // 16

typedef __attribute__((ext_vector_type(8))) short bf16x8;
typedef __attribute__((ext_vector_type(4))) float f32x4;

__device__ inline ushort f2bf(float f) {
  union { float f; unsigned u; } v; v.f = f;
  unsigned u = v.u;
  unsigned r = (u + 0x7fffu + ((u >> 16) & 1u)) >> 16;
  return (ushort)r;
}

// ---------------- embedding: resid = wte[ids] + wpe ----------------
__global__ __launch_bounds__(256) void k_embed(const int* __restrict__ ids,
    const float* __restrict__ wte, const float* __restrict__ wpe,
    float* __restrict__ resid) {
  const int nd4 = DD / 4; // 192
  int i = blockIdx.x * 256 + threadIdx.x;
  if (i >= MROWS * nd4) return;
  int m = i / nd4, d4 = i - m * nd4;
  int l = m & (LL - 1);
  int tok = ids[m];
  float4 a = ((const float4*)wte)[(size_t)tok * nd4 + d4];
  float4 b = ((const float4*)wpe)[(size_t)l * nd4 + d4];
  float4 o; o.x = a.x + b.x; o.y = a.y + b.y; o.z = a.z + b.z; o.w = a.w + b.w;
  ((float4*)resid)[i] = o;
}

// ---------------- block reduction helper (256 threads = 4 waves) ----------------
__device__ inline float block_sum(float v, volatile float* red) {
  #pragma unroll
  for (int o = 32; o > 0; o >>= 1) v += __shfl_down(v, o);
  if ((threadIdx.x & 63) == 0) red[threadIdx.x >> 6] = v;
  __syncthreads();
  float t = red[0] + red[1] + red[2] + red[3];
  __syncthreads();
  return t;
}

// ---------------- fused residual add + layernorm -> bf16 ----------------
__global__ __launch_bounds__(256) void k_ln(const float* __restrict__ hid,
    float* __restrict__ resid, const float* __restrict__ g, const float* __restrict__ b,
    ushort* __restrict__ hbf, int addHidden) {
  __shared__ float red[4];
  int m = blockIdx.x, t = threadIdx.x;
  size_t base = (size_t)m * DD;
  float x0 = resid[base + t], x1 = resid[base + t + 256], x2 = resid[base + t + 512];
  if (addHidden) {
    x0 += hid[base + t]; x1 += hid[base + t + 256]; x2 += hid[base + t + 512];
    resid[base + t] = x0; resid[base + t + 256] = x1; resid[base + t + 512] = x2;
  }
  float S  = block_sum(x0 + x1 + x2, red);
  float S2 = block_sum(x0*x0 + x1*x1 + x2*x2, red);
  float mu = S * (1.f / DD);
  float var = S2 * (1.f / DD) - mu * mu;
  float rs = rsqrtf(var + EPSV);
  hbf[base + t]       = f2bf((x0 - mu) * rs * g[t]       + b[t]);
  hbf[base + t + 256] = f2bf((x1 - mu) * rs * g[t + 256] + b[t + 256]);
  hbf[base + t + 512] = f2bf((x2 - mu) * rs * g[t + 512] + b[t + 512]);
}

// ---------------- generic NT bf16 MFMA GEMM: C[m,n] = sum_k A[m,k]*B[n,k] ----------------
__global__ __launch_bounds__(256) void k_gemm(const ushort* __restrict__ A,
    const ushort* __restrict__ Bw, float* __restrict__ C, int M, int N, int K) {
  __shared__ short lA[64][40];
  __shared__ short lB[64][40];
  int tid = threadIdx.x;
  int tm = blockIdx.y * 64, tn = blockIdx.x * 64;
  int wid = tid >> 6, lane = tid & 63;
  int wr = (wid >> 1) * 32, wc = (wid & 1) * 32;
  int fr = lane & 15, kg = lane >> 4;
  int ldr = tid >> 2, ldc = (tid & 3) * 8;
  f32x4 acc[2][2];
  #pragma unroll
  for (int mi = 0; mi < 2; ++mi)
    #pragma unroll
    for (int ni = 0; ni < 2; ++ni)
      acc[mi][ni] = {0.f, 0.f, 0.f, 0.f};

  for (int k0 = 0; k0 < K; k0 += 32) {
    __syncthreads();
    bf16x8 va = *(const bf16x8*)(A + (size_t)(tm + ldr) * K + k0 + ldc);
    short z = 0;
    bf16x8 vb = {z, z, z, z, z, z, z, z};
    int brow = tn + ldr;
    if (brow < N) vb = *(const bf16x8*)(Bw + (size_t)brow * K + k0 + ldc);
    *(bf16x8*)&lA[ldr][ldc] = va;
    *(bf16x8*)&lB[ldr][ldc] = vb;
    __syncthreads();
    bf16x8 a0 = *(const bf16x8*)&lA[wr + fr][kg * 8];
    bf16x8 a1 = *(const bf16x8*)&lA[wr + 16 + fr][kg * 8];
    bf16x8 b0 = *(const bf16x8*)&lB[wc + fr][kg * 8];
    bf16x8 b1 = *(const bf16x8*)&lB[wc + 16 + fr][kg * 8];
    acc[0][0] = __builtin_amdgcn_mfma_f32_16x16x32_bf16(a0, b0, acc[0][0], 0, 0, 0);
    acc[0][1] = __builtin_amdgcn_mfma_f32_16x16x32_bf16(a0, b1, acc[0][1], 0, 0, 0);
    acc[1][0] = __builtin_amdgcn_mfma_f32_16x16x32_bf16(a1, b0, acc[1][0], 0, 0, 0);
    acc[1][1] = __builtin_amdgcn_mfma_f32_16x16x32_bf16(a1, b1, acc[1][1], 0, 0, 0);
  }
  int crow0 = tm + wr + (lane >> 4) * 4;
  int ccol0 = tn + wc + fr;
  #pragma unroll
  for (int mi = 0; mi < 2; ++mi)
    #pragma unroll
    for (int ni = 0; ni < 2; ++ni) {
      int cc = ccol0 + ni * 16;
      if (cc < N) {
        #pragma unroll
        for (int j = 0; j < 4; ++j)
          C[(size_t)(crow0 + mi * 16 + j) * N + cc] = acc[mi][ni][j];
      }
    }
}

// ---------------- causal depthwise conv (K=4) + silu, writes f32 + bf16 ----------------
__global__ __launch_bounds__(256) void k_conv(const float* __restrict__ xz,
    const float* __restrict__ cW, const float* __restrict__ cb,
    float* __restrict__ xif, ushort* __restrict__ xibf, int layer) {
  int i = blockIdx.x * 256 + threadIdx.x;
  if (i >= MROWS * DI) return;
  int c = i % DI;
  int m = i / DI;
  int l = m & (LL - 1);
  const float* w = cW + ((size_t)layer * DI + c) * KC;
  float acc = cb[(size_t)layer * DI + c];
  #pragma unroll
  for (int k = 0; k < KC; ++k) {
    int ll = l - (KC - 1) + k;
    if (ll >= 0) acc += xz[(size_t)(m - (KC - 1) + k) * E2 + c] * w[k];
  }
  float sg = 1.f / (1.f + __expf(-acc));
  float v = acc * sg;
  xif[i] = v;
  xibf[i] = f2bf(v);
}

// ---------------- weight f32 -> bf16 (vectorized x4) ----------------
__global__ __launch_bounds__(256) void k_cvt4(const float* __restrict__ s,
    ushort* __restrict__ d, int n4) {
  int i = blockIdx.x * 256 + threadIdx.x;
  if (i >= n4) return;
  float4 v = ((const float4*)s)[i];
  ushort4 o = { f2bf(v.x), f2bf(v.y), f2bf(v.z), f2bf(v.w) };
  ((ushort4*)d)[i] = o;
}

// dt_W (DI x 48) -> bf16 (DI x 64), zero-padded K
__global__ __launch_bounds__(256) void k_cvt_dtw(const float* __restrict__ s,
    ushort* __restrict__ d) {
  int i = blockIdx.x * 256 + threadIdx.x;
  if (i >= DI * 64) return;
  int r = i >> 6, c = i & 63;
  d[i] = (c < RR) ? f2bf(s[r * RR + c]) : (ushort)0;
}

// dbl (MROWS x 80) first 48 cols -> dt_bf (MROWS x 64), zero-padded K
__global__ __launch_bounds__(256) void k_cvt_dta(const float* __restrict__ dblb,
    ushort* __restrict__ dtbf) {
  int i = blockIdx.x * 256 + threadIdx.x;
  if (i >= MROWS * 64) return;
  int r = i >> 6, c = i & 63;
  dtbf[i] = (c < RR) ? f2bf(dblb[r * 80 + c]) : (ushort)0;
}

// ---------------- delta = softplus(draw + dt_b), in place, x4 ----------------
__global__ __launch_bounds__(256) void k_delta(const float* __restrict__ dt_b,
    float* __restrict__ draw, int layer) {
  int i = blockIdx.x * 256 + threadIdx.x;      // over (MROWS*DI)/4
  if (i >= MROWS * DI / 4) return;
  int d4 = (i * 4) % DI;
  float4 x = ((const float4*)draw)[i];
  float4 bv = *(const float4*)(dt_b + (size_t)layer * DI + d4);
  float r[4] = { x.x + bv.x, x.y + bv.y, x.z + bv.z, x.w + bv.w };
  #pragma unroll
  for (int j = 0; j < 4; ++j) r[j] = (r[j] > 20.f) ? r[j] : log1pf(__expf(r[j]));
  float4 o = { r[0], r[1], r[2], r[3] };
  ((float4*)draw)[i] = o;
}

// ---------------- scan phase A: per-chunk local scan, h[16] in registers ----------------
// one thread per (b, chunk, d); emits h_end[16] and aprod[16]
__global__ __launch_bounds__(256) void k_scanA(const float* __restrict__ delta,
    const float* __restrict__ uf, const float* __restrict__ dblb,
    const float* __restrict__ A_log, float* __restrict__ hend,
    float* __restrict__ aprod, int layer) {
  const int DGRP = DI / 256; // 6
  int tid = threadIdx.x;
  int dgrp = blockIdx.x % DGRP;
  int chunk = (blockIdx.x / DGRP) % CHK;
  int b = blockIdx.x / (DGRP * CHK);
  int d = dgrp * 256 + tid;
  float an[16];
  {
    const float4* a4 = (const float4*)(A_log + ((size_t)layer * DI + d) * NS);
    #pragma unroll
    for (int q = 0; q < 4; ++q) {
      float4 v = a4[q];
      an[4*q]   = -__expf(v.x); an[4*q+1] = -__expf(v.y);
      an[4*q+2] = -__expf(v.z); an[4*q+3] = -__expf(v.w);
    }
  }
  float h[16], pr[16];
  #pragma unroll
  for (int n = 0; n < 16; ++n) { h[n] = 0.f; pr[n] = 1.f; }
  int l0 = chunk * LC;
  size_t rowd = ((size_t)b * LL + l0) * DI + d;
  size_t rowb = ((size_t)b * LL + l0) * 80;
  for (int l = 0; l < LC; ++l) {
    float dl = delta[rowd], uv = uf[rowd];
    float du = dl * uv;
    float Bv[16];
    {
      const float4* b4 = (const float4*)(dblb + rowb + RR);
      #pragma unroll
      for (int q = 0; q < 4; ++q) {
        float4 v = b4[q];
        Bv[4*q] = v.x; Bv[4*q+1] = v.y; Bv[4*q+2] = v.z; Bv[4*q+3] = v.w;
      }
    }
    #pragma unroll
    for (int n = 0; n < 16; ++n) {
      float a = __expf(dl * an[n]);
      h[n] = h[n] * a + du * Bv[n];
      pr[n] *= a;
    }
    rowd += DI; rowb += 80;
  }
  size_t o = (((size_t)b * CHK + chunk) * DI + d) * NS;
  #pragma unroll
  for (int q = 0; q < 4; ++q) {
    float4 vh = { h[4*q], h[4*q+1], h[4*q+2], h[4*q+3] };
    float4 vp = { pr[4*q], pr[4*q+1], pr[4*q+2], pr[4*q+3] };
    ((float4*)(hend + o))[q] = vh;
    ((float4*)(aprod + o))[q] = vp;
  }
}

// ---------------- scan phase B: sequential combine across chunks ----------------
__global__ __launch_bounds__(256) void k_scanB(const float* __restrict__ hend,
    const float* __restrict__ aprod, float* __restrict__ hin) {
  int i = blockIdx.x * 256 + threadIdx.x;  // over BB*DI*NS
  if (i >= BB * DI * NS) return;
  int dn = i % (DI * NS);
  int b = i / (DI * NS);
  float h = 0.f;
  size_t stride = (size_t)DI * NS;
  size_t idx = (size_t)b * CHK * stride + dn;
  for (int c = 0; c < CHK; ++c) {
    hin[idx] = h;
    h = hend[idx] + aprod[idx] * h;
    idx += stride;
  }
}

// ---------------- scan phase C: local scan from h_in, fused y + gate -> bf16 ----------------
__global__ __launch_bounds__(256) void k_scanC(const float* __restrict__ delta,
    const float* __restrict__ uf, const float* __restrict__ dblb,
    const float* __restrict__ xz, const float* __restrict__ A_log,
    const float* __restrict__ Dres, const float* __restrict__ hin,
    ushort* __restrict__ ybf, int layer) {
  const int DGRP = DI / 256; // 6
  int tid = threadIdx.x;
  int dgrp = blockIdx.x % DGRP;
  int chunk = (blockIdx.x / DGRP) % CHK;
  int b = blockIdx.x / (DGRP * CHK);
  int d = dgrp * 256 + tid;
  float an[16];
  {
    const float4* a4 = (const float4*)(A_log + ((size_t)layer * DI + d) * NS);
    #pragma unroll
    for (int q = 0; q < 4; ++q) {
      float4 v = a4[q];
      an[4*q]   = -__expf(v.x); an[4*q+1] = -__expf(v.y);
      an[4*q+2] = -__expf(v.z); an[4*q+3] = -__expf(v.w);
    }
  }
  float h[16];
  {
    size_t o = (((size_t)b * CHK + chunk) * DI + d) * NS;
    #pragma unroll
    for (int q = 0; q < 4; ++q) {
      float4 v = ((const float4*)(hin + o))[q];
      h[4*q] = v.x; h[4*q+1] = v.y; h[4*q+2] = v.z; h[4*q+3] = v.w;
    }
  }
  float dresv = Dres[(size_t)layer * DI + d];
  int l0 = chunk * LC;
  size_t rowd = ((size_t)b * LL + l0) * DI + d;
  size_t rowb = ((size_t)b * LL + l0) * 80;
  size_t rowz = ((size_t)b * LL + l0) * E2 + DI + d;
  for (int l = 0; l < LC; ++l) {
    float dl = delta[rowd], uv = uf[rowd];
    float du = dl * uv;
    float Bv[16], Cv[16];
    {
      const float4* b4 = (const float4*)(dblb + rowb + RR);
      #pragma unroll
      for (int q = 0; q < 4; ++q) {
        float4 v = b4[q];
        Bv[4*q] = v.x; Bv[4*q+1] = v.y; Bv[4*q+2] = v.z; Bv[4*q+3] = v.w;
        float4 w = b4[q + 4];
        Cv[4*q] = w.x; Cv[4*q+1] = w.y; Cv[4*q+2] = w.z; Cv[4*q+3] = w.w;
      }
    }
    float y = 0.f;
    #pragma unroll
    for (int n = 0; n < 16; ++n) {
      float a = __expf(dl * an[n]);
      h[n] = h[n] * a + du * Bv[n];
      y += h[n] * Cv[n];
    }
    float zv = xz[rowz];
    float yt = y + uv * dresv;
    float sg = 1.f / (1.f + __expf(-zv));
    ybf[rowd] = f2bf(yt * (zv * sg));
    rowd += DI; rowb += 80; rowz += E2;
  }
}

// ---------------- final: resid += hidden; out = LN(LN(resid,nf),fin) ----------------
__global__ __launch_bounds__(256) void k_final(const float* __restrict__ resid,
    const float* __restrict__ hid, const float* __restrict__ nfg,
    const float* __restrict__ nfb, const float* __restrict__ fig,
    const float* __restrict__ fib, float* __restrict__ out) {
  __shared__ float red[4];
  int m = blockIdx.x, t = threadIdx.x;
  size_t base = (size_t)m * DD;
  float x0 = resid[base + t]       + hid[base + t];
  float x1 = resid[base + t + 256] + hid[base + t + 256];
  float x2 = resid[base + t + 512] + hid[base + t + 512];
  float S  = block_sum(x0 + x1 + x2, red);
  float S2 = block_sum(x0*x0 + x1*x1 + x2*x2, red);
  float mu = S * (1.f / DD);
  float var = S2 * (1.f / DD) - mu * mu;
  float rs = rsqrtf(var + EPSV);
  float t0 = (x0 - mu) * rs * nfg[t]       + nfb[t];
  float t1 = (x1 - mu) * rs * nfg[t + 256] + nfb[t + 256];
  float t2 = (x2 - mu) * rs * nfg[t + 512] + nfb[t + 512];
  S  = block_sum(t0 + t1 + t2, red);
  S2 = block_sum(t0*t0 + t1*t1 + t2*t2, red);
  mu = S * (1.f / DD);
  var = S2 * (1.f / DD) - mu * mu;
  rs = rsqrtf(var + EPSV);
  out[base + t]       = (t0 - mu) * rs * fig[t]       + fib[t];
  out[base + t + 256] = (t1 - mu) * rs * fig[t + 256] + fib[t + 256];
  out[base + t + 512] = (t2 - mu) * rs * fig[t + 512] + fib[t + 512];
}

extern "C" void kernel_launch(void* const* d_in, const int* in_sizes, int n_in,
                              void* d_out, int out_size, void* d_ws, size_t ws_size,
                              hipStream_t stream) {
  const int*   ids    = (const int*)  d_in[0];
  const float* wte    = (const float*)d_in[1];
  const float* wpe    = (const float*)d_in[2];
  const float* ln_g   = (const float*)d_in[3];
  const float* ln_b   = (const float*)d_in[4];
  const float* in_W   = (const float*)d_in[5];
  const float* conv_W = (const float*)d_in[6];
  const float* conv_b = (const float*)d_in[7];
  const float* xp_W   = (const float*)d_in[8];
  const float* dt_W   = (const float*)d_in[9];
  const float* dt_b   = (const float*)d_in[10];
  const float* A_log  = (const float*)d_in[11];
  const float* Dres   = (const float*)d_in[12];
  const float* out_W  = (const float*)d_in[13];
  const float* nf_g   = (const float*)d_in[14];
  const float* nf_b   = (const float*)d_in[15];
  const float* fin_g  = (const float*)d_in[16];
  const float* fin_b  = (const float*)d_in[17];

  char* p = (char*)d_ws;
  auto take = [&](size_t bytes) {
    char* r = p; p += (bytes + 255) & ~(size_t)255; return r;
  };
  float*  resid  = (float*) take((size_t)MROWS * DD * 4);
  float*  hidden = (float*) take((size_t)MROWS * DD * 4);
  ushort* h_bf   = (ushort*)take((size_t)MROWS * DD * 2);
  float*  xz     = (float*) take((size_t)MROWS * E2 * 4);
  float*  xif    = (float*) take((size_t)MROWS * DI * 4);
  ushort* xibf   = (ushort*)take((size_t)MROWS * DI * 2);
  float*  dblb   = (float*) take((size_t)MROWS * 80 * 4);
  ushort* dtbf   = (ushort*)take((size_t)MROWS * 64 * 2);
  float*  draw   = (float*) take((size_t)MROWS * DI * 4);
  ushort* ybf    = (ushort*)take((size_t)MROWS * DI * 2);
  ushort* wInBf  = (ushort*)take((size_t)E2 * DD * 2);
  ushort* wXpBf  = (ushort*)take((size_t)80 * DI * 2);
  ushort* wDtBf  = (ushort*)take((size_t)DI * 64 * 2);
  ushort* wOutBf = (ushort*)take((size_t)DD * DI * 2);
  float*  hend   = (float*) take((size_t)BB * CHK * DI * NS * 4);
  float*  aprod  = (float*) take((size_t)BB * CHK * DI * NS * 4);
  float*  hin    = (float*) take((size_t)BB * CHK * DI * NS * 4);

  k_embed<<<(MROWS * (DD / 4) + 255) / 256, 256, 0, stream>>>(ids, wte, wpe, resid);

  const int scanGrid = BB * CHK * (DI / 256); // 768

  for (int i = 0; i < NLAYER; ++i) {
    k_cvt4<<<((E2 * DD / 4) + 255) / 256, 256, 0, stream>>>(
        in_W + (size_t)i * E2 * DD, wInBf, E2 * DD / 4);
    k_cvt4<<<((80 * DI / 4) + 255) / 256, 256, 0, stream>>>(
        xp_W + (size_t)i * 80 * DI, wXpBf, 80 * DI / 4);
    k_cvt_dtw<<<((DI * 64) + 255) / 256, 256, 0, stream>>>(
        dt_W + (size_t)i * DI * RR, wDtBf);
    k_cvt4<<<((DD * DI / 4) + 255) / 256, 256, 0, stream>>>(
        out_W + (size_t)i * DD * DI, wOutBf, DD * DI / 4);

    k_ln<<<MROWS, 256, 0, stream>>>(hidden, resid, ln_g + (size_t)i * DD,
                                    ln_b + (size_t)i * DD, h_bf, i > 0 ? 1 : 0);

    { dim3 g((E2 + 63) / 64, MROWS / 64);
      k_gemm<<<g, 256, 0, stream>>>(h_bf, wInBf, xz, MROWS, E2, DD); }

    k_conv<<<((MROWS * DI) + 255) / 256, 256, 0, stream>>>(
        xz, conv_W, conv_b, xif, xibf, i);

    { dim3 g((80 + 63) / 64, MROWS / 64);
      k_gemm<<<g, 256, 0, stream>>>(xibf, wXpBf, dblb, MROWS, 80, DI); }

    k_cvt_dta<<<((MROWS * 64) + 255) / 256, 256, 0, stream>>>(dblb, dtbf);

    { dim3 g((DI + 63) / 64, MROWS / 64);
      k_gemm<<<g, 256, 0, stream>>>(dtbf, wDtBf, draw, MROWS, DI, 64); }

    k_delta<<<((MROWS * DI / 4) + 255) / 256, 256, 0, stream>>>(dt_b, draw, i);

    k_scanA<<<scanGrid, 256, 0, stream>>>(draw, xif, dblb, A_log, hend, aprod, i);
    k_scanB<<<(BB * DI * NS + 255) / 256, 256, 0, stream>>>(hend, aprod, hin);
    k_scanC<<<scanGrid, 256, 0, stream>>>(draw, xif, dblb, xz, A_log, Dres,
                                          hin, ybf, i);

    { dim3 g((DD + 63) / 64, MROWS / 64);
      k_gemm<<<g, 256, 0, stream>>>(ybf, wOutBf, hidden, MROWS, DD, DI); }
  }

  k_final<<<MROWS, 256, 0, stream>>>(resid, hidden, nf_g, nf_b,
                                     fin_g, fin_b, (float*)d_out);
}

// Round 3
// 1562.778 us; speedup vs baseline: 3.7359x; 1.3707x over previous
//
#include <hip/hip_runtime.h>

#define BB 4
#define LL 512
#define DD 768
#define NLAYER 12
#define DI 1536
#define NS 16
#define KC 4
#define RR 48
#define MROWS (BB*LL)   // 2048
#define E2 (2*DI)       // 3072
#define EPSV 1e-5f
#define CH2 16          // chunks per sequence in fused scan
#define LC2 (LL/CH2)    // 32 steps per chunk

typedef __attribute__((ext_vector_type(8))) short bf16x8;
typedef __attribute__((ext_vector_type(4))) float f32x4;

#define GLL16(g, l) __builtin_amdgcn_global_load_lds( \
    (const __attribute__((address_space(1))) void*)(g), \
    (__attribute__((address_space(3))) void*)(l), 16, 0, 0)

__device__ inline ushort f2bf(float f) {
  union { float f; unsigned u; } v; v.f = f;
  unsigned u = v.u;
  unsigned r = (u + 0x7fffu + ((u >> 16) & 1u)) >> 16;
  return (ushort)r;
}
__device__ inline float bf2f(ushort u) {
  union { unsigned u; float f; } v; v.u = ((unsigned)u) << 16; return v.f;
}

// ---------------- embedding: resid = wte[ids] + wpe ----------------
__global__ __launch_bounds__(256) void k_embed(const int* __restrict__ ids,
    const float* __restrict__ wte, const float* __restrict__ wpe,
    float* __restrict__ resid) {
  const int nd4 = DD / 4; // 192
  int i = blockIdx.x * 256 + threadIdx.x;
  if (i >= MROWS * nd4) return;
  int m = i / nd4, d4 = i - m * nd4;
  int l = m & (LL - 1);
  int tok = ids[m];
  float4 a = ((const float4*)wte)[(size_t)tok * nd4 + d4];
  float4 b = ((const float4*)wpe)[(size_t)l * nd4 + d4];
  float4 o; o.x = a.x + b.x; o.y = a.y + b.y; o.z = a.z + b.z; o.w = a.w + b.w;
  ((float4*)resid)[i] = o;
}

// ---------------- block reduction helper (256 threads = 4 waves) ----------------
__device__ inline float block_sum(float v, volatile float* red) {
  #pragma unroll
  for (int o = 32; o > 0; o >>= 1) v += __shfl_down(v, o);
  if ((threadIdx.x & 63) == 0) red[threadIdx.x >> 6] = v;
  __syncthreads();
  float t = red[0] + red[1] + red[2] + red[3];
  __syncthreads();
  return t;
}

// ---------------- fused residual add (2 partials) + layernorm -> bf16 ----------------
__global__ __launch_bounds__(256) void k_ln(const float* __restrict__ h0,
    const float* __restrict__ h1,
    float* __restrict__ resid, const float* __restrict__ g, const float* __restrict__ b,
    ushort* __restrict__ hbf, int addHidden) {
  __shared__ float red[4];
  int m = blockIdx.x, t = threadIdx.x;
  size_t base = (size_t)m * DD;
  float x0 = resid[base + t], x1 = resid[base + t + 256], x2 = resid[base + t + 512];
  if (addHidden) {
    x0 += h0[base + t]       + h1[base + t];
    x1 += h0[base + t + 256] + h1[base + t + 256];
    x2 += h0[base + t + 512] + h1[base + t + 512];
    resid[base + t] = x0; resid[base + t + 256] = x1; resid[base + t + 512] = x2;
  }
  float S  = block_sum(x0 + x1 + x2, red);
  float S2 = block_sum(x0*x0 + x1*x1 + x2*x2, red);
  float mu = S * (1.f / DD);
  float var = S2 * (1.f / DD) - mu * mu;
  float rs = rsqrtf(var + EPSV);
  hbf[base + t]       = f2bf((x0 - mu) * rs * g[t]       + b[t]);
  hbf[base + t + 256] = f2bf((x1 - mu) * rs * g[t + 256] + b[t + 256]);
  hbf[base + t + 512] = f2bf((x2 - mu) * rs * g[t + 512] + b[t + 512]);
}

// ---------------- 128x128 MFMA GEMM (m97 structure), NT, bf16 in ----------------
// A: M x K bf16 rm, Bw: N x K bf16 rm. M%128==0, N%128==0, K%32==0.
// grid (N/128, M/128, splits); kSteps = (K/splits)/32; OM=0: f32 partials, OM=1: bf16.
template<int OM>
__global__ __launch_bounds__(256) void k_gemm128(const ushort* __restrict__ A,
    const ushort* __restrict__ Bw, void* __restrict__ Cv, int N, int K, int kSteps) {
  __shared__ ushort lA[128 * 32];
  __shared__ ushort lB[128 * 32];
  int tid = threadIdx.x;
  int wid = tid >> 6, lane = tid & 63;
  int tm = blockIdx.y * 128, tn = blockIdx.x * 128;
  int kBase = blockIdx.z * kSteps * 32;
  int wr = (wid >> 1) * 64, wc = (wid & 1) * 64;
  int fr = lane & 15, kg = lane >> 4;
  int srow = lane >> 2;          // staging row within 16-row segment
  int scol = (lane & 3) * 8;     // staging col (elements)
  f32x4 acc[4][4];
  #pragma unroll
  for (int mi = 0; mi < 4; ++mi)
    #pragma unroll
    for (int ni = 0; ni < 4; ++ni)
      acc[mi][ni] = {0.f, 0.f, 0.f, 0.f};

  int rs0 = wid * 2, rs1 = wid * 2 + 1;   // this wave's two 16-row segments
  for (int ks = 0; ks < kSteps; ++ks) {
    int k0 = kBase + ks * 32;
    GLL16(A  + (size_t)(tm + rs0 * 16 + srow) * K + k0 + scol, &lA[rs0 * 512]);
    GLL16(A  + (size_t)(tm + rs1 * 16 + srow) * K + k0 + scol, &lA[rs1 * 512]);
    GLL16(Bw + (size_t)(tn + rs0 * 16 + srow) * K + k0 + scol, &lB[rs0 * 512]);
    GLL16(Bw + (size_t)(tn + rs1 * 16 + srow) * K + k0 + scol, &lB[rs1 * 512]);
    __syncthreads();
    bf16x8 af[4], bf[4];
    #pragma unroll
    for (int mi = 0; mi < 4; ++mi)
      af[mi] = *(const bf16x8*)&lA[(wr + mi * 16 + fr) * 32 + kg * 8];
    #pragma unroll
    for (int ni = 0; ni < 4; ++ni)
      bf[ni] = *(const bf16x8*)&lB[(wc + ni * 16 + fr) * 32 + kg * 8];
    #pragma unroll
    for (int mi = 0; mi < 4; ++mi)
      #pragma unroll
      for (int ni = 0; ni < 4; ++ni)
        acc[mi][ni] = __builtin_amdgcn_mfma_f32_16x16x32_bf16(af[mi], bf[ni], acc[mi][ni], 0, 0, 0);
    __syncthreads();
  }
  int crow0 = tm + wr + kg * 4;
  int ccol0 = tn + wc + fr;
  if (OM == 0) {
    float* C = (float*)Cv + (size_t)blockIdx.z * ((size_t)gridDim.y * 128) * N;
    #pragma unroll
    for (int mi = 0; mi < 4; ++mi)
      #pragma unroll
      for (int ni = 0; ni < 4; ++ni)
        #pragma unroll
        for (int j = 0; j < 4; ++j)
          C[(size_t)(crow0 + mi * 16 + j) * N + ccol0 + ni * 16] = acc[mi][ni][j];
  } else {
    ushort* C = (ushort*)Cv;
    #pragma unroll
    for (int mi = 0; mi < 4; ++mi)
      #pragma unroll
      for (int ni = 0; ni < 4; ++ni)
        #pragma unroll
        for (int j = 0; j < 4; ++j)
          C[(size_t)(crow0 + mi * 16 + j) * N + ccol0 + ni * 16] = f2bf(acc[mi][ni][j]);
  }
}

// ---------------- 64x64 NT GEMM, f32 partial out (split-K), N bounds-checked ----------------
__global__ __launch_bounds__(256) void k_gemm64_part(const ushort* __restrict__ A,
    const ushort* __restrict__ Bw, float* __restrict__ Cp, int N, int K, int kSteps) {
  __shared__ short lA[64][40];
  __shared__ short lB[64][40];
  int tid = threadIdx.x;
  int tm = blockIdx.y * 64, tn = blockIdx.x * 64;
  int kBase = blockIdx.z * kSteps * 32;
  int M = gridDim.y * 64;
  float* C = Cp + (size_t)blockIdx.z * M * N;
  int wid = tid >> 6, lane = tid & 63;
  int wr = (wid >> 1) * 32, wc = (wid & 1) * 32;
  int fr = lane & 15, kg = lane >> 4;
  int ldr = tid >> 2, ldc = (tid & 3) * 8;
  f32x4 acc[2][2];
  #pragma unroll
  for (int mi = 0; mi < 2; ++mi)
    #pragma unroll
    for (int ni = 0; ni < 2; ++ni)
      acc[mi][ni] = {0.f, 0.f, 0.f, 0.f};

  for (int ks = 0; ks < kSteps; ++ks) {
    int k0 = kBase + ks * 32;
    __syncthreads();
    bf16x8 va = *(const bf16x8*)(A + (size_t)(tm + ldr) * K + k0 + ldc);
    short z = 0;
    bf16x8 vb = {z, z, z, z, z, z, z, z};
    int brow = tn + ldr;
    if (brow < N) vb = *(const bf16x8*)(Bw + (size_t)brow * K + k0 + ldc);
    *(bf16x8*)&lA[ldr][ldc] = va;
    *(bf16x8*)&lB[ldr][ldc] = vb;
    __syncthreads();
    bf16x8 a0 = *(const bf16x8*)&lA[wr + fr][kg * 8];
    bf16x8 a1 = *(const bf16x8*)&lA[wr + 16 + fr][kg * 8];
    bf16x8 b0 = *(const bf16x8*)&lB[wc + fr][kg * 8];
    bf16x8 b1 = *(const bf16x8*)&lB[wc + 16 + fr][kg * 8];
    acc[0][0] = __builtin_amdgcn_mfma_f32_16x16x32_bf16(a0, b0, acc[0][0], 0, 0, 0);
    acc[0][1] = __builtin_amdgcn_mfma_f32_16x16x32_bf16(a0, b1, acc[0][1], 0, 0, 0);
    acc[1][0] = __builtin_amdgcn_mfma_f32_16x16x32_bf16(a1, b0, acc[1][0], 0, 0, 0);
    acc[1][1] = __builtin_amdgcn_mfma_f32_16x16x32_bf16(a1, b1, acc[1][1], 0, 0, 0);
  }
  int crow0 = tm + wr + kg * 4;
  int ccol0 = tn + wc + fr;
  #pragma unroll
  for (int mi = 0; mi < 2; ++mi)
    #pragma unroll
    for (int ni = 0; ni < 2; ++ni) {
      int cc = ccol0 + ni * 16;
      if (cc < N) {
        #pragma unroll
        for (int j = 0; j < 4; ++j)
          C[(size_t)(crow0 + mi * 16 + j) * N + cc] = acc[mi][ni][j];
      }
    }
}

// ---------------- 64x64 NT GEMM for dt: epilogue delta = softplus(acc + dt_b) ----------------
__global__ __launch_bounds__(256) void k_gemm64_dt(const ushort* __restrict__ A,
    const ushort* __restrict__ Bw, float* __restrict__ delta,
    const float* __restrict__ dtb, int N, int K) {
  __shared__ short lA[64][40];
  __shared__ short lB[64][40];
  int tid = threadIdx.x;
  int tm = blockIdx.y * 64, tn = blockIdx.x * 64;
  int wid = tid >> 6, lane = tid & 63;
  int wr = (wid >> 1) * 32, wc = (wid & 1) * 32;
  int fr = lane & 15, kg = lane >> 4;
  int ldr = tid >> 2, ldc = (tid & 3) * 8;
  f32x4 acc[2][2];
  #pragma unroll
  for (int mi = 0; mi < 2; ++mi)
    #pragma unroll
    for (int ni = 0; ni < 2; ++ni)
      acc[mi][ni] = {0.f, 0.f, 0.f, 0.f};

  for (int k0 = 0; k0 < K; k0 += 32) {
    __syncthreads();
    bf16x8 va = *(const bf16x8*)(A + (size_t)(tm + ldr) * K + k0 + ldc);
    bf16x8 vb = *(const bf16x8*)(Bw + (size_t)(tn + ldr) * K + k0 + ldc);
    *(bf16x8*)&lA[ldr][ldc] = va;
    *(bf16x8*)&lB[ldr][ldc] = vb;
    __syncthreads();
    bf16x8 a0 = *(const bf16x8*)&lA[wr + fr][kg * 8];
    bf16x8 a1 = *(const bf16x8*)&lA[wr + 16 + fr][kg * 8];
    bf16x8 b0 = *(const bf16x8*)&lB[wc + fr][kg * 8];
    bf16x8 b1 = *(const bf16x8*)&lB[wc + 16 + fr][kg * 8];
    acc[0][0] = __builtin_amdgcn_mfma_f32_16x16x32_bf16(a0, b0, acc[0][0], 0, 0, 0);
    acc[0][1] = __builtin_amdgcn_mfma_f32_16x16x32_bf16(a0, b1, acc[0][1], 0, 0, 0);
    acc[1][0] = __builtin_amdgcn_mfma_f32_16x16x32_bf16(a1, b0, acc[1][0], 0, 0, 0);
    acc[1][1] = __builtin_amdgcn_mfma_f32_16x16x32_bf16(a1, b1, acc[1][1], 0, 0, 0);
  }
  int crow0 = tm + wr + kg * 4;
  int ccol0 = tn + wc + fr;
  #pragma unroll
  for (int mi = 0; mi < 2; ++mi)
    #pragma unroll
    for (int ni = 0; ni < 2; ++ni) {
      int cc = ccol0 + ni * 16;
      #pragma unroll
      for (int j = 0; j < 4; ++j) {
        float x = acc[mi][ni][j] + dtb[cc];
        float sp = (x > 20.f) ? x : log1pf(__expf(x));
        delta[(size_t)(crow0 + mi * 16 + j) * N + cc] = sp;
      }
    }
}

// ---------------- causal depthwise conv (K=4) + silu: bf16 in, bf16 out ----------------
__global__ __launch_bounds__(256) void k_conv(const ushort* __restrict__ xz,
    const float* __restrict__ cW, const float* __restrict__ cb,
    ushort* __restrict__ xibf, int layer) {
  int i = blockIdx.x * 256 + threadIdx.x;
  if (i >= MROWS * DI) return;
  int c = i % DI;
  int m = i / DI;
  int l = m & (LL - 1);
  const float* w = cW + ((size_t)layer * DI + c) * KC;
  float w0 = w[0], w1 = w[1], w2 = w[2], w3 = w[3];
  float acc = cb[(size_t)layer * DI + c];
  if (l >= 3) {
    size_t base = (size_t)(m - 3) * E2 + c;
    acc += bf2f(xz[base]) * w0 + bf2f(xz[base + E2]) * w1 +
           bf2f(xz[base + 2 * E2]) * w2 + bf2f(xz[base + 3 * E2]) * w3;
  } else {
    #pragma unroll
    for (int k = 0; k < KC; ++k) {
      int ll = l - (KC - 1) + k;
      if (ll >= 0) acc += bf2f(xz[(size_t)(m - (KC - 1) + k) * E2 + c]) *
                          ((k == 0) ? w0 : (k == 1) ? w1 : (k == 2) ? w2 : w3);
    }
  }
  float sg = 1.f / (1.f + __expf(-acc));
  xibf[i] = f2bf(acc * sg);
}

// ---------------- weight f32 -> bf16 (vectorized x4), all layers at once ----------------
__global__ __launch_bounds__(256) void k_cvt4(const float* __restrict__ s,
    ushort* __restrict__ d, int n4) {
  int i = blockIdx.x * 256 + threadIdx.x;
  if (i >= n4) return;
  float4 v = ((const float4*)s)[i];
  ushort4 o = { f2bf(v.x), f2bf(v.y), f2bf(v.z), f2bf(v.w) };
  ((ushort4*)d)[i] = o;
}

// dt_W (NL*DI x 48) -> bf16 (NL*DI x 64), zero-padded K
__global__ __launch_bounds__(256) void k_cvt_dtw(const float* __restrict__ s,
    ushort* __restrict__ d, int nRows) {
  int i = blockIdx.x * 256 + threadIdx.x;
  if (i >= nRows * 64) return;
  int r = i >> 6, c = i & 63;
  d[i] = (c < RR) ? f2bf(s[(size_t)r * RR + c]) : (ushort)0;
}

// ---------------- combine xp split-K partials -> dblb f32 + dtbf bf16(padded) ----------------
__global__ __launch_bounds__(256) void k_comb_xp(const float* __restrict__ part,
    float* __restrict__ dblb, ushort* __restrict__ dtbf) {
  int i = blockIdx.x * 256 + threadIdx.x;
  if (i >= MROWS * 80) return;
  const int S = MROWS * 80;
  float s = part[i] + part[i + S] + part[i + 2 * S] + part[i + 3 * S];
  dblb[i] = s;
  int m = i / 80, c = i - m * 80;
  if (c < RR) dtbf[(size_t)m * 64 + c] = f2bf(s);
  else if (c < 64) dtbf[(size_t)m * 64 + c] = 0;
}

// ---------------- fused selective scan: local scan + chunk combine + rescan ----------------
// block: 256 threads = CH2(16) chunks x 16 d-lanes. grid: (DI/16, BB)
__global__ __launch_bounds__(256) void k_scan_f(const float* __restrict__ delta,
    const ushort* __restrict__ ubf, const float* __restrict__ dblb,
    const ushort* __restrict__ xz, const float* __restrict__ A_log,
    const float* __restrict__ Dres, ushort* __restrict__ ybf, int layer) {
  __shared__ float shH[16 * 257];
  __shared__ float shP[16 * 257];
  int tid = threadIdx.x;
  int dloc = tid & 15, chunk = tid >> 4;
  int d = blockIdx.x * 16 + dloc;
  int b = blockIdx.y;
  float an[16];
  {
    const float4* a4 = (const float4*)(A_log + ((size_t)layer * DI + d) * NS);
    #pragma unroll
    for (int q = 0; q < 4; ++q) {
      float4 v = a4[q];
      an[4*q]   = -__expf(v.x); an[4*q+1] = -__expf(v.y);
      an[4*q+2] = -__expf(v.z); an[4*q+3] = -__expf(v.w);
    }
  }
  int l0 = chunk * LC2;
  size_t rowd0 = ((size_t)b * LL + l0) * DI + d;
  size_t rowb0 = ((size_t)b * LL + l0) * 80 + RR;

  // ---- phase A: local scan of this chunk ----
  float h[16], pr[16];
  #pragma unroll
  for (int n = 0; n < 16; ++n) { h[n] = 0.f; pr[n] = 1.f; }
  {
    size_t rd = rowd0, rb = rowb0;
    float dl = delta[rd];
    float uv = bf2f(ubf[rd]);
    float4 b0 = *(const float4*)(dblb + rb),     b1 = *(const float4*)(dblb + rb + 4);
    float4 b2 = *(const float4*)(dblb + rb + 8), b3 = *(const float4*)(dblb + rb + 12);
    for (int l = 0; l < LC2; ++l) {
      float dlc = dl, uvc = uv;
      float4 c0 = b0, c1 = b1, c2 = b2, c3 = b3;
      if (l + 1 < LC2) {
        rd += DI; rb += 80;
        dl = delta[rd]; uv = bf2f(ubf[rd]);
        b0 = *(const float4*)(dblb + rb);     b1 = *(const float4*)(dblb + rb + 4);
        b2 = *(const float4*)(dblb + rb + 8); b3 = *(const float4*)(dblb + rb + 12);
      }
      float du = dlc * uvc;
      float Bv[16] = { c0.x, c0.y, c0.z, c0.w, c1.x, c1.y, c1.z, c1.w,
                       c2.x, c2.y, c2.z, c2.w, c3.x, c3.y, c3.z, c3.w };
      #pragma unroll
      for (int n = 0; n < 16; ++n) {
        float a = __expf(dlc * an[n]);
        h[n] = h[n] * a + du * Bv[n];
        pr[n] *= a;
      }
    }
  }
  {
    int base = dloc * 257 + chunk * 16;
    #pragma unroll
    for (int n = 0; n < 16; ++n) { shH[base + n] = h[n]; shP[base + n] = pr[n]; }
  }
  __syncthreads();

  // ---- phase B: sequential combine across chunks (256 thr = 16 d x 16 n) ----
  {
    int n2 = tid & 15, dl2 = tid >> 4;
    float hh = 0.f;
    int base = dl2 * 257;
    for (int c = 0; c < CH2; ++c) {
      int idx = base + c * 16 + n2;
      float t = shH[idx], p = shP[idx];
      shH[idx] = hh;          // h_in for chunk c
      hh = t + p * hh;
    }
  }
  __syncthreads();

  // ---- phase C: rescan from corrected h_in, fused y + gate -> bf16 ----
  {
    int base = dloc * 257 + chunk * 16;
    #pragma unroll
    for (int n = 0; n < 16; ++n) h[n] = shH[base + n];
  }
  float dresv = Dres[(size_t)layer * DI + d];
  {
    size_t rd = rowd0, rb = rowb0;
    size_t rz = ((size_t)b * LL + l0) * E2 + DI + d;
    float dl = delta[rd];
    float uv = bf2f(ubf[rd]);
    float4 b0 = *(const float4*)(dblb + rb),      b1 = *(const float4*)(dblb + rb + 4);
    float4 b2 = *(const float4*)(dblb + rb + 8),  b3 = *(const float4*)(dblb + rb + 12);
    float4 e0 = *(const float4*)(dblb + rb + 16), e1 = *(const float4*)(dblb + rb + 20);
    float4 e2 = *(const float4*)(dblb + rb + 24), e3 = *(const float4*)(dblb + rb + 28);
    for (int l = 0; l < LC2; ++l) {
      float dlc = dl, uvc = uv;
      float4 c0 = b0, c1 = b1, c2 = b2, c3 = b3;
      float4 f0 = e0, f1 = e1, f2 = e2, f3 = e3;
      size_t rdc = rd, rzc = rz;
      if (l + 1 < LC2) {
        rd += DI; rb += 80; rz += E2;
        dl = delta[rd]; uv = bf2f(ubf[rd]);
        b0 = *(const float4*)(dblb + rb);      b1 = *(const float4*)(dblb + rb + 4);
        b2 = *(const float4*)(dblb + rb + 8);  b3 = *(const float4*)(dblb + rb + 12);
        e0 = *(const float4*)(dblb + rb + 16); e1 = *(const float4*)(dblb + rb + 20);
        e2 = *(const float4*)(dblb + rb + 24); e3 = *(const float4*)(dblb + rb + 28);
      }
      float du = dlc * uvc;
      float Bv[16] = { c0.x, c0.y, c0.z, c0.w, c1.x, c1.y, c1.z, c1.w,
                       c2.x, c2.y, c2.z, c2.w, c3.x, c3.y, c3.z, c3.w };
      float Cv[16] = { f0.x, f0.y, f0.z, f0.w, f1.x, f1.y, f1.z, f1.w,
                       f2.x, f2.y, f2.z, f2.w, f3.x, f3.y, f3.z, f3.w };
      float y = 0.f;
      #pragma unroll
      for (int n = 0; n < 16; ++n) {
        float a = __expf(dlc * an[n]);
        h[n] = h[n] * a + du * Bv[n];
        y += h[n] * Cv[n];
      }
      float zv = bf2f(xz[rzc]);
      float yt = y + uvc * dresv;
      float sg = 1.f / (1.f + __expf(-zv));
      ybf[rdc] = f2bf(yt * (zv * sg));
    }
  }
}

// ---------------- final: resid += h0+h1; out = LN(LN(resid,nf),fin) ----------------
__global__ __launch_bounds__(256) void k_final(const float* __restrict__ resid,
    const float* __restrict__ h0, const float* __restrict__ h1,
    const float* __restrict__ nfg, const float* __restrict__ nfb,
    const float* __restrict__ fig, const float* __restrict__ fib,
    float* __restrict__ out) {
  __shared__ float red[4];
  int m = blockIdx.x, t = threadIdx.x;
  size_t base = (size_t)m * DD;
  float x0 = resid[base + t]       + h0[base + t]       + h1[base + t];
  float x1 = resid[base + t + 256] + h0[base + t + 256] + h1[base + t + 256];
  float x2 = resid[base + t + 512] + h0[base + t + 512] + h1[base + t + 512];
  float S  = block_sum(x0 + x1 + x2, red);
  float S2 = block_sum(x0*x0 + x1*x1 + x2*x2, red);
  float mu = S * (1.f / DD);
  float var = S2 * (1.f / DD) - mu * mu;
  float rs = rsqrtf(var + EPSV);
  float t0 = (x0 - mu) * rs * nfg[t]       + nfb[t];
  float t1 = (x1 - mu) * rs * nfg[t + 256] + nfb[t + 256];
  float t2 = (x2 - mu) * rs * nfg[t + 512] + nfb[t + 512];
  S  = block_sum(t0 + t1 + t2, red);
  S2 = block_sum(t0*t0 + t1*t1 + t2*t2, red);
  mu = S * (1.f / DD);
  var = S2 * (1.f / DD) - mu * mu;
  rs = rsqrtf(var + EPSV);
  out[base + t]       = (t0 - mu) * rs * fig[t]       + fib[t];
  out[base + t + 256] = (t1 - mu) * rs * fig[t + 256] + fib[t + 256];
  out[base + t + 512] = (t2 - mu) * rs * fig[t + 512] + fib[t + 512];
}

extern "C" void kernel_launch(void* const* d_in, const int* in_sizes, int n_in,
                              void* d_out, int out_size, void* d_ws, size_t ws_size,
                              hipStream_t stream) {
  const int*   ids    = (const int*)  d_in[0];
  const float* wte    = (const float*)d_in[1];
  const float* wpe    = (const float*)d_in[2];
  const float* ln_g   = (const float*)d_in[3];
  const float* ln_b   = (const float*)d_in[4];
  const float* in_W   = (const float*)d_in[5];
  const float* conv_W = (const float*)d_in[6];
  const float* conv_b = (const float*)d_in[7];
  const float* xp_W   = (const float*)d_in[8];
  const float* dt_W   = (const float*)d_in[9];
  const float* dt_b   = (const float*)d_in[10];
  const float* A_log  = (const float*)d_in[11];
  const float* Dres   = (const float*)d_in[12];
  const float* out_W  = (const float*)d_in[13];
  const float* nf_g   = (const float*)d_in[14];
  const float* nf_b   = (const float*)d_in[15];
  const float* fin_g  = (const float*)d_in[16];
  const float* fin_b  = (const float*)d_in[17];

  char* p = (char*)d_ws;
  auto take = [&](size_t bytes) {
    char* r = p; p += (bytes + 255) & ~(size_t)255; return r;
  };
  float*  resid  = (float*) take((size_t)MROWS * DD * 4);
  float*  hidP   = (float*) take((size_t)2 * MROWS * DD * 4);   // out-proj split-K partials
  ushort* h_bf   = (ushort*)take((size_t)MROWS * DD * 2);
  ushort* xz     = (ushort*)take((size_t)MROWS * E2 * 2);
  ushort* xibf   = (ushort*)take((size_t)MROWS * DI * 2);
  float*  xpPart = (float*) take((size_t)4 * MROWS * 80 * 4);
  float*  dblb   = (float*) take((size_t)MROWS * 80 * 4);
  ushort* dtbf   = (ushort*)take((size_t)MROWS * 64 * 2);
  float*  delta  = (float*) take((size_t)MROWS * DI * 4);
  ushort* ybf    = (ushort*)take((size_t)MROWS * DI * 2);
  ushort* wInBf  = (ushort*)take((size_t)NLAYER * E2 * DD * 2);
  ushort* wXpBf  = (ushort*)take((size_t)NLAYER * 80 * DI * 2);
  ushort* wDtBf  = (ushort*)take((size_t)NLAYER * DI * 64 * 2);
  ushort* wOutBf = (ushort*)take((size_t)NLAYER * DD * DI * 2);

  // all-layer weight conversions (4 dispatches)
  k_cvt4<<<(NLAYER * E2 * DD / 4 + 255) / 256, 256, 0, stream>>>(in_W, wInBf, NLAYER * E2 * DD / 4);
  k_cvt4<<<(NLAYER * 80 * DI / 4 + 255) / 256, 256, 0, stream>>>(xp_W, wXpBf, NLAYER * 80 * DI / 4);
  k_cvt_dtw<<<(NLAYER * DI * 64 + 255) / 256, 256, 0, stream>>>(dt_W, wDtBf, NLAYER * DI);
  k_cvt4<<<(NLAYER * DD * DI / 4 + 255) / 256, 256, 0, stream>>>(out_W, wOutBf, NLAYER * DD * DI / 4);

  k_embed<<<(MROWS * (DD / 4) + 255) / 256, 256, 0, stream>>>(ids, wte, wpe, resid);

  for (int i = 0; i < NLAYER; ++i) {
    k_ln<<<MROWS, 256, 0, stream>>>(hidP, hidP + (size_t)MROWS * DD, resid,
                                    ln_g + (size_t)i * DD, ln_b + (size_t)i * DD,
                                    h_bf, i > 0 ? 1 : 0);

    { dim3 g(E2 / 128, MROWS / 128, 1);   // 24 x 16
      k_gemm128<1><<<g, 256, 0, stream>>>(h_bf, wInBf + (size_t)i * E2 * DD,
                                          (void*)xz, E2, DD, DD / 32); }

    k_conv<<<((MROWS * DI) + 255) / 256, 256, 0, stream>>>(xz, conv_W, conv_b, xibf, i);

    { dim3 g(2, MROWS / 64, 4);           // N=80 -> 2 tiles, split-K 4
      k_gemm64_part<<<g, 256, 0, stream>>>(xibf, wXpBf + (size_t)i * 80 * DI,
                                           xpPart, 80, DI, DI / 32 / 4); }

    k_comb_xp<<<(MROWS * 80 + 255) / 256, 256, 0, stream>>>(xpPart, dblb, dtbf);

    { dim3 g(DI / 64, MROWS / 64);        // 24 x 32
      k_gemm64_dt<<<g, 256, 0, stream>>>(dtbf, wDtBf + (size_t)i * DI * 64,
                                         delta, dt_b + (size_t)i * DI, DI, 64); }

    { dim3 g(DI / 16, BB);                // 96 x 4
      k_scan_f<<<g, 256, 0, stream>>>(delta, xibf, dblb, xz, A_log, Dres, ybf, i); }

    { dim3 g(DD / 128, MROWS / 128, 2);   // 6 x 16 x splitK2
      k_gemm128<0><<<g, 256, 0, stream>>>(ybf, wOutBf + (size_t)i * DD * DI,
                                          (void*)hidP, DD, DI, DI / 32 / 2); }
  }

  k_final<<<MROWS, 256, 0, stream>>>(resid, hidP, hidP + (size_t)MROWS * DD,
                                     nf_g, nf_b, fin_g, fin_b, (float*)d_out);
}